// Round 1
// baseline (69.771 us; speedup 1.0000x reference)
//
#include <hip/hip_runtime.h>

// out[b,t] = -sum_{i=0}^{15} lpc[b, t/160, i] * x[b, t-i],  x[<0] = 0
// B=1024, T=2400, N=16, F=160. All float32.
//
// One thread -> 16 consecutive outputs (four float4 stores). F=160 divisible
// by 16, so all 16 outputs share one lpc row. x window x[t-16 .. t+15] is 8
// aligned float4 loads (64B-aligned since t is a multiple of 16).
// Per-output load traffic: (8+4)*16B / 16 = 12 B  (was 20 B at OPT=8).
// 1D grid: exactly B * (T/16) = 153600 threads -> 600 blocks, no tail.

__global__ __launch_bounds__(256) void lpc_pred_kernel(
    const float* __restrict__ xt,   // [B, T]
    const float* __restrict__ lpc,  // [B, T/F, N]
    float* __restrict__ out)        // [B, T]
{
    constexpr int T = 2400;
    constexpr int N = 16;
    constexpr int F = 160;
    constexpr int FRAMES = T / F;   // 15
    constexpr int OPT = 16;         // outputs per thread
    constexpr int GPR = T / OPT;    // 150 groups per row

    const int tid = blockIdx.x * 256 + threadIdx.x;   // exactly B*GPR threads
    const int b = tid / GPR;
    const int j = tid - b * GPR;
    const int t = j * OPT;

    const float* __restrict__ xrow = xt + (size_t)b * T;
    const float* __restrict__ crow = lpc + ((size_t)b * FRAMES + (t / F)) * N;

    // 16 coefficients: 4 aligned float4 loads (crow is 64B-aligned).
    float cc[16];
    {
        const float4* cp = (const float4*)crow;
        #pragma unroll
        for (int k = 0; k < 4; ++k) {
            float4 v = cp[k];
            cc[4 * k + 0] = v.x; cc[4 * k + 1] = v.y;
            cc[4 * k + 2] = v.z; cc[4 * k + 3] = v.w;
        }
    }

    // xv[m] = x[t - 16 + m], m in [0, 32)
    float xv[32];
    if (t >= 16) {
        const float4* xp = (const float4*)(xrow + t - 16);
        #pragma unroll
        for (int k = 0; k < 8; ++k) {
            float4 v = xp[k];
            xv[4 * k + 0] = v.x; xv[4 * k + 1] = v.y;
            xv[4 * k + 2] = v.z; xv[4 * k + 3] = v.w;
        }
    } else {
        // only j == 0 per row hits this (zero-pad region, t = 0)
        #pragma unroll
        for (int m = 0; m < 32; ++m) {
            int g = t - 16 + m;
            xv[m] = (g >= 0) ? xrow[g] : 0.0f;
        }
    }

    // acc[d] = -sum_i cc[i] * x[t + d - i]; x[t+d-i] = xv[16 + d - i]
    float acc[16];
    #pragma unroll
    for (int d = 0; d < OPT; ++d) {
        float s = 0.0f;
        #pragma unroll
        for (int i = 0; i < N; ++i) {
            s += cc[i] * xv[16 + d - i];
        }
        acc[d] = -s;
    }

    float* orow = out + (size_t)b * T + t;
    #pragma unroll
    for (int q = 0; q < 4; ++q) {
        *(float4*)(orow + 4 * q) =
            make_float4(acc[4 * q + 0], acc[4 * q + 1],
                        acc[4 * q + 2], acc[4 * q + 3]);
    }
}

extern "C" void kernel_launch(void* const* d_in, const int* in_sizes, int n_in,
                              void* d_out, int out_size, void* d_ws, size_t ws_size,
                              hipStream_t stream) {
    const float* xt  = (const float*)d_in[0];
    const float* lpc = (const float*)d_in[1];
    float* out = (float*)d_out;

    constexpr int B = 1024;
    constexpr int T = 2400;
    constexpr int OPT = 16;
    constexpr int THREADS = B * (T / OPT);  // 153600

    dim3 grid(THREADS / 256);  // 600 blocks, exact
    dim3 block(256);
    lpc_pred_kernel<<<grid, block, 0, stream>>>(xt, lpc, out);
}